// Round 1
// baseline (1372.173 us; speedup 1.0000x reference)
//
#include <hip/hip_runtime.h>

#define NN 20000      // nodes
#define NE 320000     // edges
#define NB 128        // graphs
// EMB = 256 fixed throughout

__device__ __forceinline__ void atomAddF(float* p, float v) { unsafeAtomicAdd(p, v); }

// ---------------------------------------------------------------------------
// Edge prep: degree histogram, x_e = segsum(e_v, tgt), rbf (padded to 12/row)
__global__ void k_edge_prep(const int* __restrict__ ai, const float* __restrict__ e,
                            int* __restrict__ deg, float* __restrict__ x_e,
                            float* __restrict__ rbf) {
    int idx = blockIdx.x * 256 + threadIdx.x;
    if (idx >= NE) return;
    int tgt = ai[2 * idx + 1];
    atomicAdd(&deg[tgt], 1);
    float4 ev = ((const float4*)e)[idx];
    atomAddF(&x_e[tgt * 3 + 0], ev.x);
    atomAddF(&x_e[tgt * 3 + 1], ev.y);
    atomAddF(&x_e[tgt * 3 + 2], ev.z);
    float d = ev.w;
#pragma unroll
    for (int k = 0; k < 12; k++) {
        float c = (8.0f / 9.0f) * (float)k;
        float t = d - c;
        rbf[idx * 12 + k] = (k < 10) ? expf(-10.0f * t * t) : 0.0f;
    }
}

// ---------------------------------------------------------------------------
// Node prep: x_s = element_emb[x], x_v = ones, cnt/u_s_sum atomics
__global__ void k_node_prep(const int* __restrict__ x, const int* __restrict__ gid,
                            const float* __restrict__ element_emb,
                            const float* __restrict__ graph_emb,
                            float* __restrict__ x_s, float* __restrict__ xv_init,
                            float* __restrict__ cnt, float* __restrict__ u_s_sum) {
    int n = blockIdx.x, tid = threadIdx.x;
    int xe = x[n];
    x_s[n * 256 + tid] = element_emb[xe * 256 + tid];
    if (tid < 12) xv_init[n * 12 + tid] = 1.0f;
    if (tid == 0) atomAddF(&cnt[gid[n]], 1.0f);
    if (tid < 3) atomAddF(&u_s_sum[gid[n] * 3 + tid], graph_emb[xe * 3 + tid]);
}

// ---------------------------------------------------------------------------
// Exclusive prefix sum of deg -> off  (single block, 1024 threads)
__global__ void k_scan(const int* __restrict__ deg, int* __restrict__ off) {
    __shared__ int s[1024];
    __shared__ int carry_s;
    int tid = threadIdx.x;
    if (tid == 0) carry_s = 0;
    __syncthreads();
    for (int base = 0; base < NN; base += 1024) {
        int i = base + tid;
        int v = (i < NN) ? deg[i] : 0;
        s[tid] = v;
        __syncthreads();
#pragma unroll
        for (int d = 1; d < 1024; d <<= 1) {
            int t = (tid >= d) ? s[tid - d] : 0;
            __syncthreads();
            s[tid] += t;
            __syncthreads();
        }
        int tot = s[1023];
        int c0 = carry_s;
        if (i < NN) off[i] = c0 + s[tid] - v;
        __syncthreads();
        if (tid == 0) carry_s = c0 + tot;
        __syncthreads();
    }
    if (tid == 0) off[NN] = carry_s;
}

// ---------------------------------------------------------------------------
__global__ void k_scatter(const int* __restrict__ ai, const int* __restrict__ off,
                          int* __restrict__ cursor, int2* __restrict__ csr) {
    int idx = blockIdx.x * 256 + threadIdx.x;
    if (idx >= NE) return;
    int src = ai[2 * idx + 0], tgt = ai[2 * idx + 1];
    int p = off[tgt] + atomicAdd(&cursor[tgt], 1);
    csr[p] = make_int2(src, idx);
}

// ---------------------------------------------------------------------------
__global__ void k_uv(const int* __restrict__ gid, const float* __restrict__ x_e,
                     float* __restrict__ u_v_sum) {
    int n = blockIdx.x * 256 + threadIdx.x;
    if (n >= NN) return;
    int b = gid[n];
    atomAddF(&u_v_sum[b * 3 + 0], x_e[n * 3 + 0]);
    atomAddF(&u_v_sum[b * 3 + 1], x_e[n * 3 + 1]);
    atomAddF(&u_v_sum[b * 3 + 2], x_e[n * 3 + 2]);
}

__global__ void k_ufin(float* __restrict__ u_s, float* __restrict__ u_v,
                       const float* __restrict__ cnt) {
    int b = threadIdx.x;  // 128
    float c = fmaxf(cnt[b], 1.0f);
#pragma unroll
    for (int k = 0; k < 3; k++) {
        u_s[b * 3 + k] /= c;
        u_v[b * 3 + k] /= c;
    }
}

// ---------------------------------------------------------------------------
// Per-layer small precompute: Wcomb = W_e @ Wm_bot (10x256), cc = b_e@Wm_bot + bm
__global__ void k_wprep(const float* __restrict__ W_e, const float* __restrict__ b_e,
                        const float* __restrict__ Wm, const float* __restrict__ bm,
                        float* __restrict__ Wcomb, float* __restrict__ cc) {
    int k = blockIdx.x, ch = threadIdx.x;
    if (k < 10) {
        float s = 0.0f;
        for (int r = 0; r < 256; r++) s = fmaf(W_e[k * 256 + r], Wm[(256 + r) * 256 + ch], s);
        Wcomb[k * 256 + ch] = s;
    } else {
        float s = bm[ch];
        for (int r = 0; r < 256; r++) s = fmaf(b_e[r], Wm[(256 + r) * 256 + ch], s);
        cc[ch] = s;
    }
}

// ---------------------------------------------------------------------------
// C[M,256] = epi( A[M,256] @ W[256,256] ); epi: +bias, relu, +resid
__global__ __launch_bounds__(256) void k_gemm(const float* __restrict__ A,
                                              const float* __restrict__ W,
                                              const float* __restrict__ bias,
                                              const float* __restrict__ resid,
                                              float* __restrict__ C, int M, int doRelu) {
    __shared__ float As[16][64];  // [k][m]
    __shared__ float Ws[16][64];  // [k][n]
    const int tid = threadIdx.x;
    const int bm0 = blockIdx.x * 64;
    const int bn0 = blockIdx.y * 64;
    const int tx = tid & 15, ty4 = tid >> 4;
    const int lr = tid & 63, lq = tid >> 6;
    float acc[4][4] = {};
    for (int k0 = 0; k0 < 256; k0 += 16) {
        float4 av = make_float4(0.f, 0.f, 0.f, 0.f);
        int arow = bm0 + lr;
        if (arow < M) av = *(const float4*)(A + arow * 256 + k0 + lq * 4);
        float4 wv = *(const float4*)(W + (k0 + ty4) * 256 + bn0 + tx * 4);
        __syncthreads();
        As[lq * 4 + 0][lr] = av.x;
        As[lq * 4 + 1][lr] = av.y;
        As[lq * 4 + 2][lr] = av.z;
        As[lq * 4 + 3][lr] = av.w;
        *(float4*)&Ws[ty4][tx * 4] = wv;
        __syncthreads();
#pragma unroll
        for (int kk = 0; kk < 16; kk++) {
            float4 a = *(const float4*)&As[kk][ty4 * 4];
            float4 b = *(const float4*)&Ws[kk][tx * 4];
            acc[0][0] = fmaf(a.x, b.x, acc[0][0]);
            acc[0][1] = fmaf(a.x, b.y, acc[0][1]);
            acc[0][2] = fmaf(a.x, b.z, acc[0][2]);
            acc[0][3] = fmaf(a.x, b.w, acc[0][3]);
            acc[1][0] = fmaf(a.y, b.x, acc[1][0]);
            acc[1][1] = fmaf(a.y, b.y, acc[1][1]);
            acc[1][2] = fmaf(a.y, b.z, acc[1][2]);
            acc[1][3] = fmaf(a.y, b.w, acc[1][3]);
            acc[2][0] = fmaf(a.z, b.x, acc[2][0]);
            acc[2][1] = fmaf(a.z, b.y, acc[2][1]);
            acc[2][2] = fmaf(a.z, b.z, acc[2][2]);
            acc[2][3] = fmaf(a.z, b.w, acc[2][3]);
            acc[3][0] = fmaf(a.w, b.x, acc[3][0]);
            acc[3][1] = fmaf(a.w, b.y, acc[3][1]);
            acc[3][2] = fmaf(a.w, b.z, acc[3][2]);
            acc[3][3] = fmaf(a.w, b.w, acc[3][3]);
        }
    }
#pragma unroll
    for (int i = 0; i < 4; i++) {
        int row = bm0 + ty4 * 4 + i;
        if (row >= M) continue;
#pragma unroll
        for (int j = 0; j < 4; j++) {
            int col = bn0 + tx * 4 + j;
            float v = acc[i][j];
            if (bias) v += bias[col];
            if (doRelu) v = fmaxf(v, 0.0f);
            if (resid) v += resid[row * 256 + col];
            C[row * 256 + col] = v;
        }
    }
}

// ---------------------------------------------------------------------------
// Fused edge kernel: one block per node (tgt), thread = channel.
// m_s = relu(t[src] + rbf@Wcomb + cc); s_accum[n] = sum m_s (direct store);
// vector path via T[d][c] = sum_e m_s*basis; new_v = Wg-contraction + bg term.
__global__ __launch_bounds__(256) void k_edge(const int2* __restrict__ csr,
                                              const int* __restrict__ off,
                                              const float* __restrict__ t,
                                              const float* __restrict__ xv_old,
                                              const float* __restrict__ rbf,
                                              const float* __restrict__ e4,
                                              const float* __restrict__ Wcomb,
                                              const float* __restrict__ cc,
                                              const float* __restrict__ Wg,
                                              const float* __restrict__ bg,
                                              float* __restrict__ s_accum,
                                              float* __restrict__ xv_new, int addResid) {
    const int n = blockIdx.x;
    const int ch = threadIdx.x;
    const int start = off[n];
    const int deg = off[n + 1] - start;
    float wc[10];
#pragma unroll
    for (int k = 0; k < 10; k++) wc[k] = Wcomb[k * 256 + ch];
    const float ccv = cc[ch];
    float wg[12];
#pragma unroll
    for (int j = 0; j < 12; j++) wg[j] = Wg[ch * 12 + j];
    float T[12] = {};
    float Tb[12] = {};  // uniform across threads (basis sums for bg term)
    float s_sum = 0.0f;

    if (deg > 0) {
        int2 se = csr[start];
        float tv = t[se.x * 256 + ch];
        float4 r0 = *(const float4*)(rbf + se.y * 12);
        float4 r1 = *(const float4*)(rbf + se.y * 12 + 4);
        float4 xv0 = *(const float4*)(xv_old + se.x * 12);
        float4 xv1 = *(const float4*)(xv_old + se.x * 12 + 4);
        float xv8 = xv_old[se.x * 12 + 8];
        float4 ev = *(const float4*)(e4 + se.y * 4);
        float r8 = rbf[se.y * 12 + 8], r9 = rbf[se.y * 12 + 9];
        for (int idx = 0; idx < deg; ++idx) {
            int nxt = (idx + 1 < deg) ? (start + idx + 1) : start;  // branch-free wrap
            int2 se_n = csr[nxt];
            float tv_n = t[se_n.x * 256 + ch];
            float4 r0n = *(const float4*)(rbf + se_n.y * 12);
            float4 r1n = *(const float4*)(rbf + se_n.y * 12 + 4);
            float r8n = rbf[se_n.y * 12 + 8], r9n = rbf[se_n.y * 12 + 9];
            float4 xv0n = *(const float4*)(xv_old + se_n.x * 12);
            float4 xv1n = *(const float4*)(xv_old + se_n.x * 12 + 4);
            float xv8n = xv_old[se_n.x * 12 + 8];
            float4 evn = *(const float4*)(e4 + se_n.y * 4);
            // ---- compute current edge ----
            float m = tv + ccv;
            m = fmaf(r0.x, wc[0], m);
            m = fmaf(r0.y, wc[1], m);
            m = fmaf(r0.z, wc[2], m);
            m = fmaf(r0.w, wc[3], m);
            m = fmaf(r1.x, wc[4], m);
            m = fmaf(r1.y, wc[5], m);
            m = fmaf(r1.z, wc[6], m);
            m = fmaf(r1.w, wc[7], m);
            m = fmaf(r8, wc[8], m);
            m = fmaf(r9, wc[9], m);
            m = fmaxf(m, 0.0f);
            s_sum += m;
            T[0] = fmaf(m, xv0.x, T[0]);  Tb[0] += xv0.x;
            T[1] = fmaf(m, xv0.y, T[1]);  Tb[1] += xv0.y;
            T[2] = fmaf(m, xv0.z, T[2]);  Tb[2] += xv0.z;
            T[3] = fmaf(m, ev.x, T[3]);   Tb[3] += ev.x;
            T[4] = fmaf(m, xv0.w, T[4]);  Tb[4] += xv0.w;
            T[5] = fmaf(m, xv1.x, T[5]);  Tb[5] += xv1.x;
            T[6] = fmaf(m, xv1.y, T[6]);  Tb[6] += xv1.y;
            T[7] = fmaf(m, ev.y, T[7]);   Tb[7] += ev.y;
            T[8] = fmaf(m, xv1.z, T[8]);  Tb[8] += xv1.z;
            T[9] = fmaf(m, xv1.w, T[9]);  Tb[9] += xv1.w;
            T[10] = fmaf(m, xv8, T[10]);  Tb[10] += xv8;
            T[11] = fmaf(m, ev.z, T[11]); Tb[11] += ev.z;
            // rotate prefetch
            se = se_n; tv = tv_n;
            r0 = r0n; r1 = r1n; r8 = r8n; r9 = r9n;
            xv0 = xv0n; xv1 = xv1n; xv8 = xv8n; ev = evn;
        }
    }
    // vp[d][o] = sum_c wg[o*4+c] * T[d*4+c]
    float vp[9];
#pragma unroll
    for (int d = 0; d < 3; d++)
#pragma unroll
        for (int o = 0; o < 3; o++) {
            float v = wg[o * 4 + 0] * T[d * 4 + 0];
            v = fmaf(wg[o * 4 + 1], T[d * 4 + 1], v);
            v = fmaf(wg[o * 4 + 2], T[d * 4 + 2], v);
            v = fmaf(wg[o * 4 + 3], T[d * 4 + 3], v);
            vp[d * 3 + o] = v;
        }
    __shared__ float red[4][9];
#pragma unroll
    for (int j = 0; j < 9; j++) {
        float v = vp[j];
        v += __shfl_down(v, 32);
        v += __shfl_down(v, 16);
        v += __shfl_down(v, 8);
        v += __shfl_down(v, 4);
        v += __shfl_down(v, 2);
        v += __shfl_down(v, 1);
        vp[j] = v;
    }
    int lane = ch & 63, wid = ch >> 6;
    if (lane == 0) {
#pragma unroll
        for (int j = 0; j < 9; j++) red[wid][j] = vp[j];
    }
    __syncthreads();
    s_accum[n * 256 + ch] = s_sum;
    if (ch < 9) {
        int d = ch / 3, o = ch % 3;
        float v = red[0][ch] + red[1][ch] + red[2][ch] + red[3][ch];
        v = fmaf(bg[o * 4 + 0], Tb[d * 4 + 0], v);
        v = fmaf(bg[o * 4 + 1], Tb[d * 4 + 1], v);
        v = fmaf(bg[o * 4 + 2], Tb[d * 4 + 2], v);
        v = fmaf(bg[o * 4 + 3], Tb[d * 4 + 3], v);
        if (addResid) v += xv_old[n * 12 + ch];
        xv_new[n * 12 + ch] = v;
    }
}

// ---------------------------------------------------------------------------
__global__ void k_pool(const int* __restrict__ gid, const float* __restrict__ x_s,
                       const float* __restrict__ x_v, float* __restrict__ pooled_s,
                       float* __restrict__ pooled_v) {
    int n = blockIdx.x, tid = threadIdx.x;
    int b = gid[n];
    atomAddF(&pooled_s[b * 256 + tid], x_s[n * 256 + tid]);
    if (tid < 9) atomAddF(&pooled_v[b * 9 + tid], x_v[n * 12 + tid]);
}

__global__ void k_out(const float* __restrict__ pooled_s, const float* __restrict__ pooled_v,
                      const float* __restrict__ u_s, const float* __restrict__ u_v,
                      const float* __restrict__ cnt, const float* __restrict__ W_v,
                      const float* __restrict__ W_s, const float* __restrict__ b_s,
                      float* __restrict__ out) {
    int b = threadIdx.x;  // 128
    float cinv = 1.0f / fmaxf(cnt[b], 1.0f);
    float os[3];
#pragma unroll
    for (int o = 0; o < 3; o++) os[o] = b_s[o];
    for (int chn = 0; chn < 256; chn++) {
        float ps = pooled_s[b * 256 + chn] * cinv;
#pragma unroll
        for (int o = 0; o < 3; o++) os[o] = fmaf(ps, W_s[chn * 3 + o], os[o]);
    }
#pragma unroll
    for (int k = 0; k < 3; k++) {
        float us = u_s[b * 3 + k];
#pragma unroll
        for (int o = 0; o < 3; o++) os[o] = fmaf(us, W_s[(256 + k) * 3 + o], os[o]);
    }
#pragma unroll
    for (int d = 0; d < 3; d++) {
        float pv0 = pooled_v[b * 9 + d * 3 + 0] * cinv;
        float pv1 = pooled_v[b * 9 + d * 3 + 1] * cinv;
        float pv2 = pooled_v[b * 9 + d * 3 + 2] * cinv;
        float pv3 = u_v[b * 3 + d];
#pragma unroll
        for (int o = 0; o < 3; o++) {
            float v = pv0 * W_v[0 * 3 + o] + pv1 * W_v[1 * 3 + o] + pv2 * W_v[2 * 3 + o] +
                      pv3 * W_v[3 * 3 + o];
            out[b * 12 + d * 4 + o] = v;
        }
        out[b * 12 + d * 4 + 3] = os[d];
    }
}

// ---------------------------------------------------------------------------
extern "C" void kernel_launch(void* const* d_in, const int* in_sizes, int n_in, void* d_out,
                              int out_size, void* d_ws, size_t ws_size, hipStream_t stream) {
    const int* x = (const int*)d_in[0];
    const int* ai = (const int*)d_in[1];
    const float* e = (const float*)d_in[2];
    const int* gid = (const int*)d_in[3];
    const float* element_emb = (const float*)d_in[5];
    const float* graph_emb = (const float*)d_in[6];
    const float* W_e = (const float*)d_in[7];
    const float* b_e = (const float*)d_in[8];
    const float *Wm[4], *bmv[4], *Wg[4], *bg[4], *Wu[4], *bu[4];
    for (int j = 0; j < 4; j++) {
        Wm[j] = (const float*)d_in[9 + 6 * j];
        bmv[j] = (const float*)d_in[10 + 6 * j];
        Wg[j] = (const float*)d_in[11 + 6 * j];
        bg[j] = (const float*)d_in[12 + 6 * j];
        Wu[j] = (const float*)d_in[13 + 6 * j];
        bu[j] = (const float*)d_in[14 + 6 * j];
    }
    const float* W_v = (const float*)d_in[33];
    const float* W_s = (const float*)d_in[34];
    const float* b_s = (const float*)d_in[35];
    float* out = (float*)d_out;

    char* ws = (char*)d_ws;
    size_t o = 0;
    auto alloc = [&](size_t bytes) -> char* {
        char* p = ws + o;
        o += (bytes + 255) / 256 * 256;
        return p;
    };
    // --- zeroed block (must stay first & contiguous) ---
    int* deg = (int*)alloc(NN * 4);
    int* cursor = (int*)alloc(NN * 4);
    float* x_e = (float*)alloc(NN * 3 * 4);
    float* cnt = (float*)alloc(NB * 4);
    float* u_s = (float*)alloc(NB * 3 * 4);
    float* u_v = (float*)alloc(NB * 3 * 4);
    float* pooled_s = (float*)alloc(NB * 256 * 4);
    float* pooled_v = (float*)alloc(NB * 9 * 4);
    size_t zeroBytes = o;
    // --- rest ---
    int* off_a = (int*)alloc((NN + 1) * 4);
    int2* csr = (int2*)alloc((size_t)NE * 8);
    float* rbf = (float*)alloc((size_t)NE * 12 * 4);
    float* t_buf = (float*)alloc((size_t)NN * 256 * 4);
    float* s_accum = (float*)alloc((size_t)NN * 256 * 4);
    float* x_s = (float*)alloc((size_t)NN * 256 * 4);
    float* xvA = (float*)alloc((size_t)NN * 12 * 4);
    float* xvB = (float*)alloc((size_t)NN * 12 * 4);
    float* Wcomb = (float*)alloc(10 * 256 * 4);
    float* ccb = (float*)alloc(256 * 4);

    hipMemsetAsync(d_ws, 0, zeroBytes, stream);

    dim3 eb((NE + 255) / 256);
    k_edge_prep<<<eb, 256, 0, stream>>>(ai, e, deg, x_e, rbf);
    k_node_prep<<<NN, 256, 0, stream>>>(x, gid, element_emb, graph_emb, x_s, xvA, cnt, u_s);
    k_scan<<<1, 1024, 0, stream>>>(deg, off_a);
    k_scatter<<<eb, 256, 0, stream>>>(ai, off_a, cursor, csr);
    k_uv<<<(NN + 255) / 256, 256, 0, stream>>>(gid, x_e, u_v);
    k_ufin<<<1, 128, 0, stream>>>(u_s, u_v, cnt);

    float* xv_cur = xvA;
    float* xv_nxt = xvB;
    dim3 ggrid((NN + 63) / 64, 4);
    for (int j = 0; j < 4; j++) {
        k_wprep<<<11, 256, 0, stream>>>(W_e, b_e, Wm[j], bmv[j], Wcomb, ccb);
        k_gemm<<<ggrid, 256, 0, stream>>>(x_s, Wm[j], nullptr, nullptr, t_buf, NN, 0);
        k_edge<<<NN, 256, 0, stream>>>(csr, off_a, t_buf, xv_cur, rbf, e, Wcomb, ccb, Wg[j],
                                       bg[j], s_accum, xv_nxt, j > 0 ? 1 : 0);
        k_gemm<<<ggrid, 256, 0, stream>>>(s_accum, Wu[j], bu[j], (j > 0) ? x_s : nullptr, x_s,
                                          NN, 1);
        float* tmp = xv_cur;
        xv_cur = xv_nxt;
        xv_nxt = tmp;
    }
    k_pool<<<NN, 256, 0, stream>>>(gid, x_s, xv_cur, pooled_s, pooled_v);
    k_out<<<1, 128, 0, stream>>>(pooled_s, pooled_v, u_s, u_v, cnt, W_v, W_s, b_s, out);
}

// Round 2
// 1310.513 us; speedup vs baseline: 1.0471x; 1.0471x over previous
//
#include <hip/hip_runtime.h>

#define NN 20000      // nodes
#define NE 320000     // edges
#define NB 128        // graphs
// EMB = 256 fixed throughout

typedef __attribute__((ext_vector_type(8))) short short8;
typedef __attribute__((ext_vector_type(4))) float floatx4;

__device__ __forceinline__ void atomAddF(float* p, float v) { unsafeAtomicAdd(p, v); }

__device__ __forceinline__ ushort f2bf(float x) {
    union { float f; unsigned u; } v; v.f = x;
    unsigned r = v.u + 0x7FFFu + ((v.u >> 16) & 1u);
    return (ushort)(r >> 16);
}
__device__ __forceinline__ float bf2f(ushort h) {
    union { float f; unsigned u; } v; v.u = ((unsigned)h) << 16;
    return v.f;
}

// ---------------------------------------------------------------------------
// Edge prep: degree histogram, x_e = segsum(e_v, tgt), rbf (padded to 12/row)
__global__ void k_edge_prep(const int* __restrict__ ai, const float* __restrict__ e,
                            int* __restrict__ deg, float* __restrict__ x_e,
                            float* __restrict__ rbf) {
    int idx = blockIdx.x * 256 + threadIdx.x;
    if (idx >= NE) return;
    int tgt = ai[2 * idx + 1];
    atomicAdd(&deg[tgt], 1);
    float4 ev = ((const float4*)e)[idx];
    atomAddF(&x_e[tgt * 3 + 0], ev.x);
    atomAddF(&x_e[tgt * 3 + 1], ev.y);
    atomAddF(&x_e[tgt * 3 + 2], ev.z);
    float d = ev.w;
#pragma unroll
    for (int k = 0; k < 12; k++) {
        float c = (8.0f / 9.0f) * (float)k;
        float t = d - c;
        rbf[idx * 12 + k] = (k < 10) ? expf(-10.0f * t * t) : 0.0f;
    }
}

// ---------------------------------------------------------------------------
// Node prep: x_s (bf16 hi/lo) = element_emb[x], x_v = ones, cnt/u_s_sum atomics
__global__ void k_node_prep(const int* __restrict__ x, const int* __restrict__ gid,
                            const float* __restrict__ element_emb,
                            const float* __restrict__ graph_emb,
                            ushort* __restrict__ xsh, ushort* __restrict__ xsl,
                            float* __restrict__ xv_init,
                            float* __restrict__ cnt, float* __restrict__ u_s_sum) {
    int n = blockIdx.x, tid = threadIdx.x;
    int xe = x[n];
    float v = element_emb[xe * 256 + tid];
    ushort h = f2bf(v);
    xsh[n * 256 + tid] = h;
    xsl[n * 256 + tid] = f2bf(v - bf2f(h));
    if (tid < 12) xv_init[n * 12 + tid] = 1.0f;
    if (tid == 0) atomAddF(&cnt[gid[n]], 1.0f);
    if (tid < 3) atomAddF(&u_s_sum[gid[n] * 3 + tid], graph_emb[xe * 3 + tid]);
}

// ---------------------------------------------------------------------------
// Exclusive prefix sum of deg -> off  (single block, 1024 threads)
__global__ void k_scan(const int* __restrict__ deg, int* __restrict__ off) {
    __shared__ int s[1024];
    __shared__ int carry_s;
    int tid = threadIdx.x;
    if (tid == 0) carry_s = 0;
    __syncthreads();
    for (int base = 0; base < NN; base += 1024) {
        int i = base + tid;
        int v = (i < NN) ? deg[i] : 0;
        s[tid] = v;
        __syncthreads();
#pragma unroll
        for (int d = 1; d < 1024; d <<= 1) {
            int t = (tid >= d) ? s[tid - d] : 0;
            __syncthreads();
            s[tid] += t;
            __syncthreads();
        }
        int tot = s[1023];
        int c0 = carry_s;
        if (i < NN) off[i] = c0 + s[tid] - v;
        __syncthreads();
        if (tid == 0) carry_s = c0 + tot;
        __syncthreads();
    }
    if (tid == 0) off[NN] = carry_s;
}

// ---------------------------------------------------------------------------
__global__ void k_scatter(const int* __restrict__ ai, const int* __restrict__ off,
                          int* __restrict__ cursor, int2* __restrict__ csr) {
    int idx = blockIdx.x * 256 + threadIdx.x;
    if (idx >= NE) return;
    int src = ai[2 * idx + 0], tgt = ai[2 * idx + 1];
    int p = off[tgt] + atomicAdd(&cursor[tgt], 1);
    csr[p] = make_int2(src, idx);
}

// ---------------------------------------------------------------------------
__global__ void k_uv(const int* __restrict__ gid, const float* __restrict__ x_e,
                     float* __restrict__ u_v_sum) {
    int n = blockIdx.x * 256 + threadIdx.x;
    if (n >= NN) return;
    int b = gid[n];
    atomAddF(&u_v_sum[b * 3 + 0], x_e[n * 3 + 0]);
    atomAddF(&u_v_sum[b * 3 + 1], x_e[n * 3 + 1]);
    atomAddF(&u_v_sum[b * 3 + 2], x_e[n * 3 + 2]);
}

__global__ void k_ufin(float* __restrict__ u_s, float* __restrict__ u_v,
                       const float* __restrict__ cnt) {
    int b = threadIdx.x;  // 128
    float c = fmaxf(cnt[b], 1.0f);
#pragma unroll
    for (int k = 0; k < 3; k++) {
        u_s[b * 3 + k] /= c;
        u_v[b * 3 + k] /= c;
    }
}

// ---------------------------------------------------------------------------
// All-layer precompute: Wcomb[j] = W_e @ Wm_bot (10x256), cc[j] = b_e@Wm_bot + bm
__global__ void k_wprep4(const float* __restrict__ W_e, const float* __restrict__ b_e,
                         const float* __restrict__ Wm0, const float* __restrict__ Wm1,
                         const float* __restrict__ Wm2, const float* __restrict__ Wm3,
                         const float* __restrict__ bm0, const float* __restrict__ bm1,
                         const float* __restrict__ bm2, const float* __restrict__ bm3,
                         float* __restrict__ Wcomb, float* __restrict__ cc) {
    int j = blockIdx.y;
    const float* Wm = (j == 0) ? Wm0 : (j == 1) ? Wm1 : (j == 2) ? Wm2 : Wm3;
    const float* bm = (j == 0) ? bm0 : (j == 1) ? bm1 : (j == 2) ? bm2 : bm3;
    float* Wc = Wcomb + j * 2560;
    float* cj = cc + j * 256;
    int k = blockIdx.x, ch = threadIdx.x;
    if (k < 10) {
        float s = 0.0f;
        for (int r = 0; r < 256; r++) s = fmaf(W_e[k * 256 + r], Wm[(256 + r) * 256 + ch], s);
        Wc[k * 256 + ch] = s;
    } else {
        float s = bm[ch];
        for (int r = 0; r < 256; r++) s = fmaf(b_e[r], Wm[(256 + r) * 256 + ch], s);
        cj[ch] = s;
    }
}

// ---------------------------------------------------------------------------
// Weight transpose + bf16 hi/lo split. mat z: W[256x256] row-major (k-major) ->
// WT planes [n][k]: hi at WT+z*131072, lo at +65536 (ushort units).
__global__ void k_wconv(const float* __restrict__ W0, const float* __restrict__ W1,
                        const float* __restrict__ W2, const float* __restrict__ W3,
                        const float* __restrict__ W4, const float* __restrict__ W5,
                        const float* __restrict__ W6, const float* __restrict__ W7,
                        ushort* __restrict__ WT) {
    const float* Ws[8] = {W0, W1, W2, W3, W4, W5, W6, W7};
    const float* W = Ws[blockIdx.z];
    ushort* outh = WT + (size_t)blockIdx.z * 131072;
    ushort* outl = outh + 65536;
    __shared__ float tile[64][65];
    int kt = blockIdx.x * 64, nt = blockIdx.y * 64;
    int c = threadIdx.x & 63, rq = threadIdx.x >> 6;
#pragma unroll
    for (int r0 = 0; r0 < 16; r0++) {
        int k = kt + rq * 16 + r0;
        tile[rq * 16 + r0][c] = W[k * 256 + nt + c];
    }
    __syncthreads();
#pragma unroll
    for (int r0 = 0; r0 < 16; r0++) {
        int n = nt + rq * 16 + r0;
        float v = tile[c][rq * 16 + r0];  // = W[kt+c][n]
        ushort h = f2bf(v);
        outh[n * 256 + kt + c] = h;
        outl[n * 256 + kt + c] = f2bf(v - bf2f(h));
    }
}

// ---------------------------------------------------------------------------
// bf16 hi/lo split-precision MFMA GEMM: C[M,256] = A[M,256] @ W[256,256]
// A given as hi/lo planes; W as transposed hi/lo planes [n][k].
// Epilogue: t-path (Cf!=null): plain fp32 store. xs-path: +bias, relu,
// +resid(hi+lo), write hi/lo planes.
__global__ __launch_bounds__(256) void k_gemm_bf16(
    const ushort* __restrict__ Ah, const ushort* __restrict__ Al,
    const ushort* __restrict__ Bh, const ushort* __restrict__ Bl,
    const float* __restrict__ bias,
    const ushort* __restrict__ Rh, const ushort* __restrict__ Rl,
    float* __restrict__ Cf, ushort* __restrict__ Coh, ushort* __restrict__ Col, int M) {
    __shared__ __align__(16) ushort As[2][128][40];
    __shared__ __align__(16) ushort Bs[2][128][40];
    const int tid = threadIdx.x;
    const int lane = tid & 63, wid = tid >> 6;
    const int bm0 = blockIdx.x * 128, bn0 = blockIdx.y * 128;
    const int wm0 = (wid & 1) * 64, wn0 = (wid >> 1) * 64;
    const int lm = lane & 15, q8 = (lane >> 4) * 8;
    floatx4 acc[4][4] = {};
    for (int k0 = 0; k0 < 256; k0 += 32) {
        __syncthreads();
#pragma unroll
        for (int c = tid; c < 512; c += 256) {
            int row = c >> 2, part = c & 3;
            uint4 vh = make_uint4(0, 0, 0, 0), vl = make_uint4(0, 0, 0, 0);
            if (bm0 + row < M) {
                int gofs = (bm0 + row) * 256 + k0 + part * 8;
                vh = *(const uint4*)(Ah + gofs);
                vl = *(const uint4*)(Al + gofs);
            }
            *(uint4*)&As[0][row][part * 8] = vh;
            *(uint4*)&As[1][row][part * 8] = vl;
        }
#pragma unroll
        for (int c = tid; c < 512; c += 256) {
            int row = c >> 2, part = c & 3;
            int gofs = (bn0 + row) * 256 + k0 + part * 8;
            *(uint4*)&Bs[0][row][part * 8] = *(const uint4*)(Bh + gofs);
            *(uint4*)&Bs[1][row][part * 8] = *(const uint4*)(Bl + gofs);
        }
        __syncthreads();
        short8 ah[4], al[4], bh[4], bl[4];
#pragma unroll
        for (int mt = 0; mt < 4; mt++) {
            ah[mt] = *(const short8*)&As[0][wm0 + mt * 16 + lm][q8];
            al[mt] = *(const short8*)&As[1][wm0 + mt * 16 + lm][q8];
        }
#pragma unroll
        for (int nt = 0; nt < 4; nt++) {
            bh[nt] = *(const short8*)&Bs[0][wn0 + nt * 16 + lm][q8];
            bl[nt] = *(const short8*)&Bs[1][wn0 + nt * 16 + lm][q8];
        }
#pragma unroll
        for (int mt = 0; mt < 4; mt++)
#pragma unroll
            for (int nt = 0; nt < 4; nt++) {
                acc[mt][nt] = __builtin_amdgcn_mfma_f32_16x16x32_bf16(ah[mt], bh[nt], acc[mt][nt], 0, 0, 0);
                acc[mt][nt] = __builtin_amdgcn_mfma_f32_16x16x32_bf16(ah[mt], bl[nt], acc[mt][nt], 0, 0, 0);
                acc[mt][nt] = __builtin_amdgcn_mfma_f32_16x16x32_bf16(al[mt], bh[nt], acc[mt][nt], 0, 0, 0);
            }
    }
    const int rq4 = (lane >> 4) * 4;
#pragma unroll
    for (int mt = 0; mt < 4; mt++) {
        int rbase = bm0 + wm0 + mt * 16 + rq4;
#pragma unroll
        for (int nt = 0; nt < 4; nt++) {
            int col = bn0 + wn0 + nt * 16 + lm;
#pragma unroll
            for (int r = 0; r < 4; r++) {
                int row = rbase + r;
                if (row >= M) continue;
                float v = acc[mt][nt][r];
                if (Cf) {
                    Cf[row * 256 + col] = v;
                } else {
                    v += bias[col];
                    v = fmaxf(v, 0.0f);
                    if (Rh) v += bf2f(Rh[row * 256 + col]) + bf2f(Rl[row * 256 + col]);
                    ushort h = f2bf(v);
                    Coh[row * 256 + col] = h;
                    Col[row * 256 + col] = f2bf(v - bf2f(h));
                }
            }
        }
    }
}

// ---------------------------------------------------------------------------
// Fused edge kernel: one block per node (tgt), thread = channel.
// Per-edge uniform data via scalar (readfirstlane) loads; Tb split across waves.
__global__ __launch_bounds__(256) void k_edge(const int2* __restrict__ csr,
                                              const int* __restrict__ off,
                                              const float* __restrict__ t,
                                              const float* __restrict__ xv_old,
                                              const float* __restrict__ rbf,
                                              const float* __restrict__ e4,
                                              const float* __restrict__ Wcomb,
                                              const float* __restrict__ cc,
                                              const float* __restrict__ Wg,
                                              const float* __restrict__ bg,
                                              ushort* __restrict__ sah,
                                              ushort* __restrict__ sal,
                                              float* __restrict__ xv_new, int addResid) {
    const int n = blockIdx.x;
    const int ch = threadIdx.x;
    const int lane = ch & 63, wid = ch >> 6;
    const int start = off[n];
    const int deg = off[n + 1] - start;
    float wc[10];
#pragma unroll
    for (int k = 0; k < 10; k++) wc[k] = Wcomb[k * 256 + ch];
    const float ccv = cc[ch];
    float wg[12];
#pragma unroll
    for (int j = 0; j < 12; j++) wg[j] = Wg[ch * 12 + j];
    float T[12] = {};
    float Tb[12] = {};
    float s_sum = 0.0f;

    if (deg > 0) {
        int2 se0 = csr[start];
        int src = __builtin_amdgcn_readfirstlane(se0.x);
        int ei = __builtin_amdgcn_readfirstlane(se0.y);
        float tv = t[src * 256 + ch];
        for (int idx = 0; idx < deg; ++idx) {
            int nxt = (idx + 1 < deg) ? (start + idx + 1) : start;
            int2 seN = csr[nxt];
            int srcN = __builtin_amdgcn_readfirstlane(seN.x);
            int eiN = __builtin_amdgcn_readfirstlane(seN.y);
            float tvN = t[srcN * 256 + ch];
            // scalar per-edge data (wave-uniform addresses)
            const float* rb = rbf + ei * 12;
            float r0 = rb[0], r1 = rb[1], r2 = rb[2], r3 = rb[3], r4 = rb[4];
            float r5 = rb[5], r6 = rb[6], r7 = rb[7], r8 = rb[8], r9 = rb[9];
            const float* bv = xv_old + src * 12;
            float b0 = bv[0], b1 = bv[1], b2 = bv[2], b3 = bv[3], b4 = bv[4];
            float b5 = bv[5], b6 = bv[6], b7 = bv[7], b8 = bv[8];
            const float* ev = e4 + ei * 4;
            float e0 = ev[0], e1 = ev[1], e2 = ev[2];
            // edge message
            float m = tv + ccv;
            m = fmaf(r0, wc[0], m);
            m = fmaf(r1, wc[1], m);
            m = fmaf(r2, wc[2], m);
            m = fmaf(r3, wc[3], m);
            m = fmaf(r4, wc[4], m);
            m = fmaf(r5, wc[5], m);
            m = fmaf(r6, wc[6], m);
            m = fmaf(r7, wc[7], m);
            m = fmaf(r8, wc[8], m);
            m = fmaf(r9, wc[9], m);
            m = fmaxf(m, 0.0f);
            s_sum += m;
            T[0] = fmaf(m, b0, T[0]);
            T[1] = fmaf(m, b1, T[1]);
            T[2] = fmaf(m, b2, T[2]);
            T[3] = fmaf(m, e0, T[3]);
            T[4] = fmaf(m, b3, T[4]);
            T[5] = fmaf(m, b4, T[5]);
            T[6] = fmaf(m, b5, T[6]);
            T[7] = fmaf(m, e1, T[7]);
            T[8] = fmaf(m, b6, T[8]);
            T[9] = fmaf(m, b7, T[9]);
            T[10] = fmaf(m, b8, T[10]);
            T[11] = fmaf(m, e2, T[11]);
            if (((idx - wid) & 3) == 0) {  // wave-uniform branch: split Tb over waves
                Tb[0] += b0;
                Tb[1] += b1;
                Tb[2] += b2;
                Tb[3] += e0;
                Tb[4] += b3;
                Tb[5] += b4;
                Tb[6] += b5;
                Tb[7] += e1;
                Tb[8] += b6;
                Tb[9] += b7;
                Tb[10] += b8;
                Tb[11] += e2;
            }
            src = srcN;
            ei = eiN;
            tv = tvN;
        }
    }
    // vp[d][o] = sum_c wg[o*4+c] * T[d*4+c]
    float vp[9];
#pragma unroll
    for (int d = 0; d < 3; d++)
#pragma unroll
        for (int o = 0; o < 3; o++) {
            float v = wg[o * 4 + 0] * T[d * 4 + 0];
            v = fmaf(wg[o * 4 + 1], T[d * 4 + 1], v);
            v = fmaf(wg[o * 4 + 2], T[d * 4 + 2], v);
            v = fmaf(wg[o * 4 + 3], T[d * 4 + 3], v);
            vp[d * 3 + o] = v;
        }
    __shared__ float red[4][9];
    __shared__ float TbS[4][12];
#pragma unroll
    for (int j = 0; j < 9; j++) {
        float v = vp[j];
        v += __shfl_down(v, 32);
        v += __shfl_down(v, 16);
        v += __shfl_down(v, 8);
        v += __shfl_down(v, 4);
        v += __shfl_down(v, 2);
        v += __shfl_down(v, 1);
        vp[j] = v;
    }
    if (lane == 0) {
#pragma unroll
        for (int j = 0; j < 9; j++) red[wid][j] = vp[j];
#pragma unroll
        for (int j = 0; j < 12; j++) TbS[wid][j] = Tb[j];
    }
    __syncthreads();
    ushort h = f2bf(s_sum);
    sah[n * 256 + ch] = h;
    sal[n * 256 + ch] = f2bf(s_sum - bf2f(h));
    if (ch < 9) {
        int d = ch / 3, o = ch % 3;
        float v = red[0][ch] + red[1][ch] + red[2][ch] + red[3][ch];
#pragma unroll
        for (int c = 0; c < 4; c++) {
            float tb = TbS[0][d * 4 + c] + TbS[1][d * 4 + c] + TbS[2][d * 4 + c] + TbS[3][d * 4 + c];
            v = fmaf(bg[o * 4 + c], tb, v);
        }
        if (addResid) v += xv_old[n * 12 + ch];
        xv_new[n * 12 + ch] = v;
    }
}

// ---------------------------------------------------------------------------
__global__ void k_pool(const int* __restrict__ gid, const ushort* __restrict__ xsh,
                       const ushort* __restrict__ xsl, const float* __restrict__ x_v,
                       float* __restrict__ pooled_s, float* __restrict__ pooled_v) {
    int n = blockIdx.x, tid = threadIdx.x;
    int b = gid[n];
    float v = bf2f(xsh[n * 256 + tid]) + bf2f(xsl[n * 256 + tid]);
    atomAddF(&pooled_s[b * 256 + tid], v);
    if (tid < 9) atomAddF(&pooled_v[b * 9 + tid], x_v[n * 12 + tid]);
}

__global__ void k_out(const float* __restrict__ pooled_s, const float* __restrict__ pooled_v,
                      const float* __restrict__ u_s, const float* __restrict__ u_v,
                      const float* __restrict__ cnt, const float* __restrict__ W_v,
                      const float* __restrict__ W_s, const float* __restrict__ b_s,
                      float* __restrict__ out) {
    int b = threadIdx.x;  // 128
    float cinv = 1.0f / fmaxf(cnt[b], 1.0f);
    float os[3];
#pragma unroll
    for (int o = 0; o < 3; o++) os[o] = b_s[o];
    for (int chn = 0; chn < 256; chn++) {
        float ps = pooled_s[b * 256 + chn] * cinv;
#pragma unroll
        for (int o = 0; o < 3; o++) os[o] = fmaf(ps, W_s[chn * 3 + o], os[o]);
    }
#pragma unroll
    for (int k = 0; k < 3; k++) {
        float us = u_s[b * 3 + k];
#pragma unroll
        for (int o = 0; o < 3; o++) os[o] = fmaf(us, W_s[(256 + k) * 3 + o], os[o]);
    }
#pragma unroll
    for (int d = 0; d < 3; d++) {
        float pv0 = pooled_v[b * 9 + d * 3 + 0] * cinv;
        float pv1 = pooled_v[b * 9 + d * 3 + 1] * cinv;
        float pv2 = pooled_v[b * 9 + d * 3 + 2] * cinv;
        float pv3 = u_v[b * 3 + d];
#pragma unroll
        for (int o = 0; o < 3; o++) {
            float v = pv0 * W_v[0 * 3 + o] + pv1 * W_v[1 * 3 + o] + pv2 * W_v[2 * 3 + o] +
                      pv3 * W_v[3 * 3 + o];
            out[b * 12 + d * 4 + o] = v;
        }
        out[b * 12 + d * 4 + 3] = os[d];
    }
}

// ---------------------------------------------------------------------------
extern "C" void kernel_launch(void* const* d_in, const int* in_sizes, int n_in, void* d_out,
                              int out_size, void* d_ws, size_t ws_size, hipStream_t stream) {
    const int* x = (const int*)d_in[0];
    const int* ai = (const int*)d_in[1];
    const float* e = (const float*)d_in[2];
    const int* gid = (const int*)d_in[3];
    const float* element_emb = (const float*)d_in[5];
    const float* graph_emb = (const float*)d_in[6];
    const float* W_e = (const float*)d_in[7];
    const float* b_e = (const float*)d_in[8];
    const float *Wm[4], *bmv[4], *Wg[4], *bg[4], *Wu[4], *bu[4];
    for (int j = 0; j < 4; j++) {
        Wm[j] = (const float*)d_in[9 + 6 * j];
        bmv[j] = (const float*)d_in[10 + 6 * j];
        Wg[j] = (const float*)d_in[11 + 6 * j];
        bg[j] = (const float*)d_in[12 + 6 * j];
        Wu[j] = (const float*)d_in[13 + 6 * j];
        bu[j] = (const float*)d_in[14 + 6 * j];
    }
    const float* W_v = (const float*)d_in[33];
    const float* W_s = (const float*)d_in[34];
    const float* b_s = (const float*)d_in[35];
    float* out = (float*)d_out;

    char* ws = (char*)d_ws;
    size_t o = 0;
    auto alloc = [&](size_t bytes) -> char* {
        char* p = ws + o;
        o += (bytes + 255) / 256 * 256;
        return p;
    };
    // --- zeroed block (must stay first & contiguous) ---
    int* deg = (int*)alloc(NN * 4);
    int* cursor = (int*)alloc(NN * 4);
    float* x_e = (float*)alloc(NN * 3 * 4);
    float* cnt = (float*)alloc(NB * 4);
    float* u_s = (float*)alloc(NB * 3 * 4);
    float* u_v = (float*)alloc(NB * 3 * 4);
    float* pooled_s = (float*)alloc(NB * 256 * 4);
    float* pooled_v = (float*)alloc(NB * 9 * 4);
    size_t zeroBytes = o;
    // --- rest ---
    int* off_a = (int*)alloc((NN + 1) * 4);
    int2* csr = (int2*)alloc((size_t)NE * 8);
    float* rbf = (float*)alloc((size_t)NE * 12 * 4);
    float* t_buf = (float*)alloc((size_t)NN * 256 * 4);
    ushort* xsh = (ushort*)alloc((size_t)NN * 256 * 2);
    ushort* xsl = (ushort*)alloc((size_t)NN * 256 * 2);
    ushort* sah = (ushort*)alloc((size_t)NN * 256 * 2);
    ushort* sal = (ushort*)alloc((size_t)NN * 256 * 2);
    float* xvA = (float*)alloc((size_t)NN * 12 * 4);
    float* xvB = (float*)alloc((size_t)NN * 12 * 4);
    float* Wcomb = (float*)alloc(4 * 10 * 256 * 4);
    float* ccb = (float*)alloc(4 * 256 * 4);
    ushort* WT = (ushort*)alloc((size_t)8 * 131072 * 2);  // 8 mats x (hi+lo) planes

    hipMemsetAsync(d_ws, 0, zeroBytes, stream);

    dim3 eb((NE + 255) / 256);
    k_edge_prep<<<eb, 256, 0, stream>>>(ai, e, deg, x_e, rbf);
    k_node_prep<<<NN, 256, 0, stream>>>(x, gid, element_emb, graph_emb, xsh, xsl, xvA, cnt, u_s);
    k_scan<<<1, 1024, 0, stream>>>(deg, off_a);
    k_scatter<<<eb, 256, 0, stream>>>(ai, off_a, cursor, csr);
    k_uv<<<(NN + 255) / 256, 256, 0, stream>>>(gid, x_e, u_v);
    k_ufin<<<1, 128, 0, stream>>>(u_s, u_v, cnt);
    k_wprep4<<<dim3(11, 4), 256, 0, stream>>>(W_e, b_e, Wm[0], Wm[1], Wm[2], Wm[3], bmv[0],
                                              bmv[1], bmv[2], bmv[3], Wcomb, ccb);
    // mats: 2j = Wm_top (rows 0..255 of Wm), 2j+1 = Wu
    k_wconv<<<dim3(4, 4, 8), 256, 0, stream>>>(Wm[0], Wu[0], Wm[1], Wu[1], Wm[2], Wu[2], Wm[3],
                                               Wu[3], WT);

    float* xv_cur = xvA;
    float* xv_nxt = xvB;
    dim3 ggrid((NN + 127) / 128, 2);
    for (int j = 0; j < 4; j++) {
        const ushort* WmT = WT + (size_t)(2 * j) * 131072;
        const ushort* WuT = WT + (size_t)(2 * j + 1) * 131072;
        k_gemm_bf16<<<ggrid, 256, 0, stream>>>(xsh, xsl, WmT, WmT + 65536, nullptr, nullptr,
                                               nullptr, t_buf, nullptr, nullptr, NN);
        k_edge<<<NN, 256, 0, stream>>>(csr, off_a, t_buf, xv_cur, rbf, e, Wcomb + j * 2560,
                                       ccb + j * 256, Wg[j], bg[j], sah, sal, xv_nxt,
                                       j > 0 ? 1 : 0);
        k_gemm_bf16<<<ggrid, 256, 0, stream>>>(sah, sal, WuT, WuT + 65536, bu[j],
                                               (j > 0) ? xsh : nullptr, (j > 0) ? xsl : nullptr,
                                               nullptr, xsh, xsl, NN);
        float* tmp = xv_cur;
        xv_cur = xv_nxt;
        xv_nxt = tmp;
    }
    k_pool<<<NN, 256, 0, stream>>>(gid, xsh, xsl, xv_cur, pooled_s, pooled_v);
    k_out<<<1, 128, 0, stream>>>(pooled_s, pooled_v, u_s, u_v, cnt, W_v, W_s, b_s, out);
}